// Round 13
// baseline (411.773 us; speedup 1.0000x reference)
//
#include <hip/hip_runtime.h>
#include <hip/hip_bf16.h>

// DenseFastGAT  B=2, N=4096, IN=OUT=256, ~1%-dense adjacency given dense.
// Single fused producer/consumer kernel (2048 blocks):
//   bids [0,512)    : GEMM  zb = bf16(x@W^T + bW) + partial ai/aj dots;
//                     threadfence + release atomicAdd(gcnt) on completion.
//   bids [512,1536) : producers — round k (0..7) builds the bitmask of row
//                     k*1024+p (16KB contiguous, 4 chunks/wave, agent-scope
//                     mask stores), then release-store flag[row]=1.
//   bids [1536,2048): consumers — 2048 waves x 4 rows (strided v+i*2048);
//                     acquire-spin on gcnt then flag[row]; wave attend
//                     (popcount compaction, softmax, zb gather unroll-8).
// Deadlock-free in any schedule: producers/GEMM never wait; consumers only
// wait on them. Attend's L2/L3 gathers overlap the adj HBM stream.
// Mask bit layout (per 1KB chunk = 256 cols): word w=comp in [0,4): bit l
// <-> j = chunk*256 + l*4 + comp. Row r = chunks [r*16, r*16+16).

#define NN   4096
#define OUTF 256
#define INF  256
#define CAP_E 128      // max edges/row; Binom(4096,0.01) max ~75, hard-guarded

typedef __attribute__((ext_vector_type(8))) short short8v;
typedef __attribute__((ext_vector_type(4))) float f32x4;

static __device__ __forceinline__ unsigned short f2bf(float f) {
    union { float f; unsigned u; } v; v.f = f;
    unsigned r = v.u + 0x7fffu + ((v.u >> 16) & 1u);   // RNE (finite inputs)
    return (unsigned short)(r >> 16);
}
static __device__ __forceinline__ float bf2f(unsigned short u) {
    union { unsigned u; float f; } v; v.u = ((unsigned)u) << 16; return v.f;
}

#define BM 64
#define BN 64
#define BK 64
#define GEMM_BLOCKS 512
#define PROD_BLOCKS 1024
#define TOTAL_BLOCKS 2048

// ---- wave-level attend for one row (R11-proven body) ----
static __device__ __forceinline__ void attendRow(
        int row, int lane,
        const unsigned long long* __restrict__ mask64,
        unsigned short* __restrict__ si, float* __restrict__ swv,
        const float* __restrict__ pai, const float* __restrict__ paj,
        float bsum, const unsigned short* __restrict__ zb,
        float* __restrict__ out) {
    const int b = row >> 12;
    unsigned long long mm = mask64[(size_t)row * 64 + lane];
    const int c = __popcll(mm);
    int incl = c;
    #pragma unroll
    for (int s = 1; s < 64; s <<= 1) {
        int t = __shfl_up(incl, s);
        if (lane >= s) incl += t;
    }
    const int cnt0 = __shfl(incl, 63);
    const int cnt = cnt0 > CAP_E ? CAP_E : cnt0;
    int pos = incl - c;
    const int jbase = (lane >> 2) * 256 + (lane & 3);
    while (mm) {
        int bit = __builtin_ctzll(mm);
        if (pos < CAP_E) si[pos] = (unsigned short)(jbase + bit * 4);
        ++pos;
        mm &= mm - 1;
    }

    const float4* pa = (const float4*)(pai + row * 8);
    const float4 u = pa[0], v2 = pa[1];
    const float AI = (u.x + u.y + u.z + u.w) + (v2.x + v2.y + v2.z + v2.w) + bsum;

    const bool h0 = lane < cnt, h1 = lane + 64 < cnt;
    float a0 = -3e38f, a1 = -3e38f;
    const float* pjb = paj + ((size_t)(b << 12)) * 8;
    if (h0) {
        const float4* q = (const float4*)(pjb + si[lane] * 8);
        float4 x0 = q[0], x1 = q[1];
        a0 = (x0.x + x0.y + x0.z + x0.w) + (x1.x + x1.y + x1.z + x1.w);
    }
    if (h1) {
        const float4* q = (const float4*)(pjb + si[lane + 64] * 8);
        float4 x0 = q[0], x1 = q[1];
        a1 = (x0.x + x0.y + x0.z + x0.w) + (x1.x + x1.y + x1.z + x1.w);
    }
    float lm = fmaxf(a0, a1);
    #pragma unroll
    for (int s = 1; s < 64; s <<= 1) lm = fmaxf(lm, __shfl_xor(lm, s));
    const float tm = AI + lm;
    const float m = tm >= 0.f ? tm : 0.2f * tm;    // leaky is monotone
    float w0 = 0.f, w1 = 0.f;
    if (h0) { float e = AI + a0; e = e >= 0.f ? e : 0.2f * e; w0 = __expf(e - m); }
    if (h1) { float e = AI + a1; e = e >= 0.f ? e : 0.2f * e; w1 = __expf(e - m); }
    float ls = w0 + w1;
    #pragma unroll
    for (int s = 1; s < 64; s <<= 1) ls += __shfl_xor(ls, s);
    const float inv = cnt ? 1.f / ls : 0.f;
    if (h0) swv[lane] = w0;
    if (h1) swv[lane + 64] = w1;

    const unsigned short* zcol = zb + ((size_t)(b << 12)) * OUTF + lane * 4;
    float4 acc = make_float4(0.f, 0.f, 0.f, 0.f);
    int p = 0;
    for (; p + 8 <= cnt; p += 8) {
        ushort4 q[8]; float w[8];
        #pragma unroll
        for (int k = 0; k < 8; ++k) {
            q[k] = *(const ushort4*)(zcol + (size_t)si[p + k] * OUTF);
            w[k] = swv[p + k];
        }
        #pragma unroll
        for (int k = 0; k < 8; ++k) {
            acc.x = fmaf(w[k], bf2f(q[k].x), acc.x);
            acc.y = fmaf(w[k], bf2f(q[k].y), acc.y);
            acc.z = fmaf(w[k], bf2f(q[k].z), acc.z);
            acc.w = fmaf(w[k], bf2f(q[k].w), acc.w);
        }
    }
    if (p + 4 <= cnt) {
        ushort4 q[4]; float w[4];
        #pragma unroll
        for (int k = 0; k < 4; ++k) {
            q[k] = *(const ushort4*)(zcol + (size_t)si[p + k] * OUTF);
            w[k] = swv[p + k];
        }
        #pragma unroll
        for (int k = 0; k < 4; ++k) {
            acc.x = fmaf(w[k], bf2f(q[k].x), acc.x);
            acc.y = fmaf(w[k], bf2f(q[k].y), acc.y);
            acc.z = fmaf(w[k], bf2f(q[k].z), acc.z);
            acc.w = fmaf(w[k], bf2f(q[k].w), acc.w);
        }
        p += 4;
    }
    for (; p < cnt; ++p) {
        int g = si[p]; float Wp = swv[p];
        ushort4 q = *(const ushort4*)(zcol + (size_t)g * OUTF);
        acc.x = fmaf(Wp, bf2f(q.x), acc.x);
        acc.y = fmaf(Wp, bf2f(q.y), acc.y);
        acc.z = fmaf(Wp, bf2f(q.z), acc.z);
        acc.w = fmaf(Wp, bf2f(q.w), acc.w);
    }
    *(float4*)(out + (size_t)row * OUTF + lane * 4) =
        make_float4(acc.x * inv, acc.y * inv, acc.z * inv, acc.w * inv);
}

__global__ __launch_bounds__(256) void gat_one(
        const float* __restrict__ x, const float* __restrict__ W,
        const float* __restrict__ bW, const float* __restrict__ wai,
        const float* __restrict__ waj, const float* __restrict__ bai,
        const float* __restrict__ baj, const float* __restrict__ adj,
        unsigned short* __restrict__ zb, float* __restrict__ pai,
        float* __restrict__ paj, unsigned long long* __restrict__ mask64,
        int* __restrict__ flags, int* __restrict__ gcnt,
        float* __restrict__ out) {
    __shared__ union {
        struct { alignas(16) unsigned short As[BM * BK];
                 alignas(16) unsigned short Bs[BN * BK]; } g;
        struct { unsigned short idx[4][CAP_E]; float w[4][CAP_E]; } a;
    } sm;
    const int tid  = threadIdx.x;
    const int lane = tid & 63;
    const int wid  = tid >> 6;
    const int bid  = blockIdx.x;

    if (bid >= GEMM_BLOCKS && bid < GEMM_BLOCKS + PROD_BLOCKS) {
        // ------------------------------ producer: 8 rounds x 1 row/block
        const int p = bid - GEMM_BLOCKS;                 // 0..1023
        const float4* a4 = (const float4*)adj;
        for (int k = 0; k < 8; ++k) {
            const int r = k * 1024 + p;
            const size_t cb = (size_t)r * 16 + wid * 4;
            #pragma unroll
            for (int c = 0; c < 4; ++c) {
                const float4 v = a4[(cb + c) * 64 + lane];
                unsigned long long b0 = __ballot(v.x > 0.f);
                unsigned long long b1 = __ballot(v.y > 0.f);
                unsigned long long b2 = __ballot(v.z > 0.f);
                unsigned long long b3 = __ballot(v.w > 0.f);
                if (lane == 0) {
                    unsigned long long* dst = mask64 + (cb + c) * 4;
                    __hip_atomic_store(dst + 0, b0, __ATOMIC_RELAXED, __HIP_MEMORY_SCOPE_AGENT);
                    __hip_atomic_store(dst + 1, b1, __ATOMIC_RELAXED, __HIP_MEMORY_SCOPE_AGENT);
                    __hip_atomic_store(dst + 2, b2, __ATOMIC_RELAXED, __HIP_MEMORY_SCOPE_AGENT);
                    __hip_atomic_store(dst + 3, b3, __ATOMIC_RELAXED, __HIP_MEMORY_SCOPE_AGENT);
                }
            }
            __syncthreads();   // drains vmcnt: all 4 waves' mask stores done
            if (tid == 0)
                __hip_atomic_store(&flags[r], 1, __ATOMIC_RELEASE, __HIP_MEMORY_SCOPE_AGENT);
        }
        return;
    }

    if (bid >= GEMM_BLOCKS + PROD_BLOCKS) {
        // ------------------------------ consumer: 4 waves x 4 rows each
        const int v = (bid - GEMM_BLOCKS - PROD_BLOCKS) * 4 + wid;  // 0..2047
        unsigned short* si = sm.a.idx[wid];
        float* swv = sm.a.w[wid];
        const float bsum = bai[0] + baj[0];
        while (__hip_atomic_load(gcnt, __ATOMIC_ACQUIRE, __HIP_MEMORY_SCOPE_AGENT)
               < GEMM_BLOCKS)
            __builtin_amdgcn_s_sleep(8);
        #pragma unroll
        for (int i = 0; i < 4; ++i) {
            const int row = v + i * 2048;
            while (__hip_atomic_load(&flags[row], __ATOMIC_ACQUIRE,
                                     __HIP_MEMORY_SCOPE_AGENT) == 0)
                __builtin_amdgcn_s_sleep(4);
            attendRow(row, lane, mask64, si, swv, pai, paj, bsum, zb, out);
        }
        return;
    }

    // ---------------------------------- GEMM (bids [0,512))
    const int rowBase = (bid & 127) * BM;
    const int colBase = (bid >> 7) * BN;
    const int wm = (wid >> 1) * 32;
    const int wn = (wid & 1) * 32;
    const int sr = tid >> 4;
    const int sc = tid & 15;

    f32x4 acc[2][2] = {};

    for (int kk = 0; kk < INF; kk += BK) {
        #pragma unroll
        for (int pass = 0; pass < BM / 16; ++pass) {
            int r = pass * 16 + sr;
            const float4 v = *(const float4*)(&x[(size_t)(rowBase + r) * INF + kk + sc * 4]);
            int off = r * 128 + ((sc * 8) ^ ((r & 7) << 4));
            *(ushort4*)((char*)sm.g.As + off) =
                make_ushort4(f2bf(v.x), f2bf(v.y), f2bf(v.z), f2bf(v.w));
        }
        #pragma unroll
        for (int pass = 0; pass < BN / 16; ++pass) {
            int r = pass * 16 + sr;
            const float4 v = *(const float4*)(&W[(size_t)(colBase + r) * INF + kk + sc * 4]);
            int off = r * 128 + ((sc * 8) ^ ((r & 7) << 4));
            *(ushort4*)((char*)sm.g.Bs + off) =
                make_ushort4(f2bf(v.x), f2bf(v.y), f2bf(v.z), f2bf(v.w));
        }
        __syncthreads();
        #pragma unroll
        for (int ks = 0; ks < 2; ++ks) {
            short8v aF[2], bF[2];
            #pragma unroll
            for (int m = 0; m < 2; ++m) {
                int row = wm + m * 16 + (lane & 15);
                int cb  = (ks * 64 + ((lane >> 4) * 16)) ^ ((row & 7) << 4);
                aF[m] = *(const short8v*)((const char*)sm.g.As + row * 128 + cb);
            }
            #pragma unroll
            for (int n = 0; n < 2; ++n) {
                int row = wn + n * 16 + (lane & 15);
                int cb  = (ks * 64 + ((lane >> 4) * 16)) ^ ((row & 7) << 4);
                bF[n] = *(const short8v*)((const char*)sm.g.Bs + row * 128 + cb);
            }
            #pragma unroll
            for (int m = 0; m < 2; ++m)
                #pragma unroll
                for (int n = 0; n < 2; ++n)
                    acc[m][n] = __builtin_amdgcn_mfma_f32_16x16x32_bf16(
                        aF[m], bF[n], acc[m][n], 0, 0, 0);
        }
        __syncthreads();
    }
    const int r4 = (lane >> 4) * 4;
    const int cW = lane & 15;
    const int col0 = colBase + wn + cW;
    const int col1 = col0 + 16;
    const float b0 = bW[col0],  b1 = bW[col1];
    const float i0 = wai[col0], i1 = wai[col1];
    const float j0 = waj[col0], j1 = waj[col1];
    const int slot = (bid >> 7) * 2 + (wid & 1);
    #pragma unroll
    for (int m = 0; m < 2; ++m) {
        #pragma unroll
        for (int r = 0; r < 4; ++r) {
            int row = rowBase + wm + m * 16 + r4 + r;
            float z0 = acc[m][0][r] + b0;
            float z1 = acc[m][1][r] + b1;
            zb[(size_t)row * OUTF + col0] = f2bf(z0);
            zb[(size_t)row * OUTF + col1] = f2bf(z1);
            float pi = z0 * i0 + z1 * i1;
            float pj = z0 * j0 + z1 * j1;
            #pragma unroll
            for (int s = 1; s < 16; s <<= 1) {
                pi += __shfl_xor(pi, s);
                pj += __shfl_xor(pj, s);
            }
            if (cW == 0) {
                pai[row * 8 + slot] = pi;
                paj[row * 8 + slot] = pj;
            }
        }
    }
    __threadfence();          // write back zb/pai/paj to coherence point
    __syncthreads();
    if (tid == 0)
        __hip_atomic_fetch_add(gcnt, 1, __ATOMIC_RELEASE, __HIP_MEMORY_SCOPE_AGENT);
}

extern "C" void kernel_launch(void* const* d_in, const int* in_sizes, int n_in,
                              void* d_out, int out_size, void* d_ws, size_t ws_size,
                              hipStream_t stream) {
    const float* x   = (const float*)d_in[0];
    const float* adj = (const float*)d_in[1];
    const float* W   = (const float*)d_in[2];
    const float* bW  = (const float*)d_in[3];
    const float* wai = (const float*)d_in[4];
    const float* bai = (const float*)d_in[5];
    const float* waj = (const float*)d_in[6];
    const float* baj = (const float*)d_in[7];
    float* out = (float*)d_out;

    char* ws = (char*)d_ws;
    unsigned short* zb   = (unsigned short*)ws;                        // 4 MB
    float* pai = (float*)(ws + (4u << 20));                            // 256 KB
    float* paj = pai + 8192 * 8;                                       // 256 KB
    unsigned long long* mask = (unsigned long long*)(ws + (5u << 20)); // 4 MB
    int* flags = (int*)(ws + (9u << 20));                              // 32 KB
    int* gcnt  = flags + 8192;                                         // 4 B

    hipMemsetAsync(flags, 0, 8192 * sizeof(int) + 64, stream);
    gat_one<<<TOTAL_BLOCKS, 256, 0, stream>>>(
        x, W, bW, wai, waj, bai, baj, adj,
        zb, pai, paj, mask, flags, gcnt, out);
}

// Round 15
// 45.949 us; speedup vs baseline: 8.9616x; 8.9616x over previous
//
#include <hip/hip_runtime.h>
#include <hip/hip_bf16.h>

// DenseFastGAT  B=2, N=4096, IN=OUT=256, ~1%-dense adjacency given dense.
//   K1 gat_pre   : block-specialized. Blocks [0,512): zb = bf16(x@W^T + bW) +
//                  partial ai/aj dots. Blocks [512,2560): adj fp32 -> bitmask
//                  via plain lane-contiguous float4 + 4 ballots per 1KB chunk.
//                  GEMM hides under the adj stream.
//   K2 gat_attend: wave per row (linear bid map). 512B bitmask/row ->
//                  popcount prefix compaction, softmax, zb gather (unroll 8).
// Mask bit layout: word w of row r (w in [0,64)) = ballot of chunk c=w>>2,
// component w&3: bit l  <->  j = (w>>2)*256 + l*4 + (w&3).
// R15 = exact restore of R11 (best: 44.96us). R13 (intra-kernel flags) and
// R14 (cooperative launch) both failed structurally on this harness.

#define NN   4096
#define OUTF 256
#define INF  256
#define CAP_E 128      // max edges/row; Binom(4096,0.01) max ~75, hard-guarded

typedef __attribute__((ext_vector_type(8))) short short8v;
typedef __attribute__((ext_vector_type(4))) float f32x4;

static __device__ __forceinline__ unsigned short f2bf(float f) {
    union { float f; unsigned u; } v; v.f = f;
    unsigned r = v.u + 0x7fffu + ((v.u >> 16) & 1u);   // RNE (finite inputs)
    return (unsigned short)(r >> 16);
}
static __device__ __forceinline__ float bf2f(unsigned short u) {
    union { unsigned u; float f; } v; v.u = ((unsigned)u) << 16; return v.f;
}

// ---------------------------------------------------------------- K1 fused
// GEMM geometry: M=8192, N=256, K=256. BM=64, BN=64, BK=64, 4 waves (2x2).
#define BM 64
#define BN 64
#define BK 64
#define GEMM_BLOCKS 512           // (8192/64) * (256/64)
#define MASK_BLOCKS 2048

__global__ __launch_bounds__(256) void gat_pre(
        const float* __restrict__ x, const float* __restrict__ W,
        const float* __restrict__ bW, const float* __restrict__ wai,
        const float* __restrict__ waj, unsigned short* __restrict__ zb,
        float* __restrict__ pai, float* __restrict__ paj,
        const float* __restrict__ adj, unsigned long long* __restrict__ mask64) {
    __shared__ alignas(16) unsigned short As[BM * BK];  // row stride 128B, XOR-swz
    __shared__ alignas(16) unsigned short Bs[BN * BK];
    const int tid  = threadIdx.x;
    const int lane = tid & 63;
    const int wid  = tid >> 6;

    if (blockIdx.x >= GEMM_BLOCKS) {
        // ---- mask path: wave streams 16 chunks of 1KB, lane-contiguous.
        const int widx = (blockIdx.x - GEMM_BLOCKS) * 4 + wid;   // 0..8191
        const float4* a4 = (const float4*)adj;
        const size_t cbase = (size_t)widx * 16;
        #pragma unroll 4
        for (int c = 0; c < 16; ++c) {
            const float4 v = a4[(cbase + c) * 64 + lane];
            unsigned long long b0 = __ballot(v.x > 0.f);
            unsigned long long b1 = __ballot(v.y > 0.f);
            unsigned long long b2 = __ballot(v.z > 0.f);
            unsigned long long b3 = __ballot(v.w > 0.f);
            if (lane == 0) {
                unsigned long long* dst = mask64 + (cbase + c) * 4;
                dst[0] = b0; dst[1] = b1; dst[2] = b2; dst[3] = b3;
            }
        }
        return;
    }

    // ---- GEMM path (blocks [0,512))
    const int rowBase = (blockIdx.x & 127) * BM;
    const int colBase = (blockIdx.x >> 7) * BN;
    const int wm = (wid >> 1) * 32;
    const int wn = (wid & 1) * 32;
    const int sr = tid >> 4;          // staging row 0..15
    const int sc = tid & 15;          // staging col-quad

    f32x4 acc[2][2] = {};

    for (int kk = 0; kk < INF; kk += BK) {
        #pragma unroll
        for (int pass = 0; pass < BM / 16; ++pass) {
            int r = pass * 16 + sr;
            const float4 v = *(const float4*)(&x[(size_t)(rowBase + r) * INF + kk + sc * 4]);
            int off = r * 128 + ((sc * 8) ^ ((r & 7) << 4));
            *(ushort4*)((char*)As + off) =
                make_ushort4(f2bf(v.x), f2bf(v.y), f2bf(v.z), f2bf(v.w));
        }
        #pragma unroll
        for (int pass = 0; pass < BN / 16; ++pass) {
            int r = pass * 16 + sr;
            const float4 v = *(const float4*)(&W[(size_t)(colBase + r) * INF + kk + sc * 4]);
            int off = r * 128 + ((sc * 8) ^ ((r & 7) << 4));
            *(ushort4*)((char*)Bs + off) =
                make_ushort4(f2bf(v.x), f2bf(v.y), f2bf(v.z), f2bf(v.w));
        }
        __syncthreads();
        #pragma unroll
        for (int ks = 0; ks < 2; ++ks) {
            short8v aF[2], bF[2];
            #pragma unroll
            for (int m = 0; m < 2; ++m) {
                int row = wm + m * 16 + (lane & 15);
                int cb  = (ks * 64 + ((lane >> 4) * 16)) ^ ((row & 7) << 4);
                aF[m] = *(const short8v*)((const char*)As + row * 128 + cb);
            }
            #pragma unroll
            for (int n = 0; n < 2; ++n) {
                int row = wn + n * 16 + (lane & 15);
                int cb  = (ks * 64 + ((lane >> 4) * 16)) ^ ((row & 7) << 4);
                bF[n] = *(const short8v*)((const char*)Bs + row * 128 + cb);
            }
            #pragma unroll
            for (int m = 0; m < 2; ++m)
                #pragma unroll
                for (int n = 0; n < 2; ++n)
                    acc[m][n] = __builtin_amdgcn_mfma_f32_16x16x32_bf16(
                        aF[m], bF[n], acc[m][n], 0, 0, 0);
        }
        __syncthreads();
    }
    // epilogue: C/D layout col=lane&15, row=(lane>>4)*4+reg
    const int r4 = (lane >> 4) * 4;
    const int cW = lane & 15;
    const int col0 = colBase + wn + cW;
    const int col1 = col0 + 16;
    const float b0 = bW[col0],  b1 = bW[col1];
    const float i0 = wai[col0], i1 = wai[col1];
    const float j0 = waj[col0], j1 = waj[col1];
    const int slot = (blockIdx.x >> 7) * 2 + (wid & 1);   // 8 x 32-col slices
    #pragma unroll
    for (int m = 0; m < 2; ++m) {
        #pragma unroll
        for (int r = 0; r < 4; ++r) {
            int row = rowBase + wm + m * 16 + r4 + r;
            float z0 = acc[m][0][r] + b0;
            float z1 = acc[m][1][r] + b1;
            zb[(size_t)row * OUTF + col0] = f2bf(z0);
            zb[(size_t)row * OUTF + col1] = f2bf(z1);
            float pi = z0 * i0 + z1 * i1;
            float pj = z0 * j0 + z1 * j1;
            #pragma unroll
            for (int s = 1; s < 16; s <<= 1) {   // 16-lane group reduce
                pi += __shfl_xor(pi, s);
                pj += __shfl_xor(pj, s);
            }
            if (cW == 0) {
                pai[row * 8 + slot] = pi;
                paj[row * 8 + slot] = pj;
            }
        }
    }
}

// ---------------------------------------------------- K2: sparse attention
// Wave per row (4/block, 2048 blocks, linear bid map). Lane holds mask word
// `lane`: j = (lane>>2)*256 + bit*4 + (lane&3). Popcount prefix-scan ->
// edge strip in per-wave LDS (no block barriers). Masked (-9e15) / sink
// (-1e9) reference terms underflow to exactly 0 for rows with edges;
// edgeless rows -> 0.
__global__ __launch_bounds__(256) void gat_attend(
        const unsigned long long* __restrict__ mask64,
        const float* __restrict__ pai, const float* __restrict__ paj,
        const float* __restrict__ bai, const float* __restrict__ baj,
        const unsigned short* __restrict__ zb, float* __restrict__ out) {
    __shared__ unsigned short s_idx[4][CAP_E];   // per-wave edge strip
    __shared__ float          s_w[4][CAP_E];
    const int tid  = threadIdx.x;
    const int lane = tid & 63;
    const int wv   = tid >> 6;
    const int row  = blockIdx.x * 4 + wv;
    const int b    = row >> 12;
    unsigned short* si = s_idx[wv];
    float* swv = s_w[wv];

    // compaction: 1 load + popcount prefix + per-lane bit extraction
    unsigned long long mm = mask64[(size_t)row * 64 + lane];
    const int c = __popcll(mm);
    int incl = c;
    #pragma unroll
    for (int s = 1; s < 64; s <<= 1) {
        int t = __shfl_up(incl, s);
        if (lane >= s) incl += t;
    }
    const int cnt0 = __shfl(incl, 63);
    const int cnt = cnt0 > CAP_E ? CAP_E : cnt0;
    int pos = incl - c;
    const int jbase = (lane >> 2) * 256 + (lane & 3);
    while (mm) {
        int bit = __builtin_ctzll(mm);
        if (pos < CAP_E) si[pos] = (unsigned short)(jbase + bit * 4);
        ++pos;
        mm &= mm - 1;
    }

    // AI = sum(pai[row]) + bai + baj  (both biases folded into the i-term)
    const float4* pa = (const float4*)(pai + row * 8);
    const float4 u = pa[0], v2 = pa[1];
    const float AI = (u.x + u.y + u.z + u.w) + (v2.x + v2.y + v2.z + v2.w)
                   + bai[0] + baj[0];

    // per-lane aj finalize for edge slots lane and lane+64 (cnt <= 128)
    const bool h0 = lane < cnt, h1 = lane + 64 < cnt;
    float a0 = -3e38f, a1 = -3e38f;
    const float* pjb = paj + ((size_t)(b << 12)) * 8;
    if (h0) {
        const float4* q = (const float4*)(pjb + si[lane] * 8);
        float4 x0 = q[0], x1 = q[1];
        a0 = (x0.x + x0.y + x0.z + x0.w) + (x1.x + x1.y + x1.z + x1.w);
    }
    if (h1) {
        const float4* q = (const float4*)(pjb + si[lane + 64] * 8);
        float4 x0 = q[0], x1 = q[1];
        a1 = (x0.x + x0.y + x0.z + x0.w) + (x1.x + x1.y + x1.z + x1.w);
    }
    float lm = fmaxf(a0, a1);
    #pragma unroll
    for (int s = 1; s < 64; s <<= 1) lm = fmaxf(lm, __shfl_xor(lm, s));
    const float tm = AI + lm;
    const float m = tm >= 0.f ? tm : 0.2f * tm;    // leaky is monotone
    float w0 = 0.f, w1 = 0.f;
    if (h0) { float e = AI + a0; e = e >= 0.f ? e : 0.2f * e; w0 = __expf(e - m); }
    if (h1) { float e = AI + a1; e = e >= 0.f ? e : 0.2f * e; w1 = __expf(e - m); }
    float ls = w0 + w1;
    #pragma unroll
    for (int s = 1; s < 64; s <<= 1) ls += __shfl_xor(ls, s);
    const float inv = cnt ? 1.f / ls : 0.f;
    if (h0) swv[lane] = w0;
    if (h1) swv[lane + 64] = w1;

    // gather: out[row][lane*4 .. +3] = inv * sum_p w_p * zb[j_p][cols]
    // unroll 8: 8 independent ushort4 loads in flight per iteration.
    const unsigned short* zcol = zb + ((size_t)(b << 12)) * OUTF + lane * 4;
    float4 acc = make_float4(0.f, 0.f, 0.f, 0.f);
    int p = 0;
    for (; p + 8 <= cnt; p += 8) {
        ushort4 q[8];
        float   w[8];
        #pragma unroll
        for (int k = 0; k < 8; ++k) {
            q[k] = *(const ushort4*)(zcol + (size_t)si[p + k] * OUTF);
            w[k] = swv[p + k];
        }
        #pragma unroll
        for (int k = 0; k < 8; ++k) {
            acc.x = fmaf(w[k], bf2f(q[k].x), acc.x);
            acc.y = fmaf(w[k], bf2f(q[k].y), acc.y);
            acc.z = fmaf(w[k], bf2f(q[k].z), acc.z);
            acc.w = fmaf(w[k], bf2f(q[k].w), acc.w);
        }
    }
    if (p + 4 <= cnt) {
        ushort4 q[4];
        float   w[4];
        #pragma unroll
        for (int k = 0; k < 4; ++k) {
            q[k] = *(const ushort4*)(zcol + (size_t)si[p + k] * OUTF);
            w[k] = swv[p + k];
        }
        #pragma unroll
        for (int k = 0; k < 4; ++k) {
            acc.x = fmaf(w[k], bf2f(q[k].x), acc.x);
            acc.y = fmaf(w[k], bf2f(q[k].y), acc.y);
            acc.z = fmaf(w[k], bf2f(q[k].z), acc.z);
            acc.w = fmaf(w[k], bf2f(q[k].w), acc.w);
        }
        p += 4;
    }
    for (; p < cnt; ++p) {
        int g = si[p]; float Wp = swv[p];
        ushort4 q = *(const ushort4*)(zcol + (size_t)g * OUTF);
        acc.x = fmaf(Wp, bf2f(q.x), acc.x);
        acc.y = fmaf(Wp, bf2f(q.y), acc.y);
        acc.z = fmaf(Wp, bf2f(q.z), acc.z);
        acc.w = fmaf(Wp, bf2f(q.w), acc.w);
    }
    *(float4*)(out + (size_t)row * OUTF + lane * 4) =
        make_float4(acc.x * inv, acc.y * inv, acc.z * inv, acc.w * inv);
}

extern "C" void kernel_launch(void* const* d_in, const int* in_sizes, int n_in,
                              void* d_out, int out_size, void* d_ws, size_t ws_size,
                              hipStream_t stream) {
    const float* x   = (const float*)d_in[0];
    const float* adj = (const float*)d_in[1];
    const float* W   = (const float*)d_in[2];
    const float* bW  = (const float*)d_in[3];
    const float* wai = (const float*)d_in[4];
    const float* bai = (const float*)d_in[5];
    const float* waj = (const float*)d_in[6];
    const float* baj = (const float*)d_in[7];
    float* out = (float*)d_out;

    char* ws = (char*)d_ws;
    unsigned short* zb   = (unsigned short*)ws;                    // 4 MB
    float* pai = (float*)(ws + (4u << 20));                        // 256 KB
    float* paj = pai + 8192 * 8;                                   // 256 KB
    unsigned long long* mask = (unsigned long long*)(ws + (5u << 20)); // 4 MB

    gat_pre<<<GEMM_BLOCKS + MASK_BLOCKS, 256, 0, stream>>>(
        x, W, bW, wai, waj, zb, pai, paj, adj, mask);
    gat_attend<<<2048, 256, 0, stream>>>(
        mask, pai, paj, bai, baj, zb, out);
}